// Round 7
// baseline (113.601 us; speedup 1.0000x reference)
//
#include <hip/hip_runtime.h>

#define NMODELS 128
#define SZ_IN 256
#define SZ_OUT 256
#define CHUNK 8
#define MAXCHUNKS 768  // >= 128 + 4096/8 worst case
#define NT 512         // 8 waves: 4 K-quarters x 2 col-halves

typedef __attribute__((ext_vector_type(4))) float f32x4;
typedef __attribute__((ext_vector_type(2))) float f32x2;

// ---------- Prep: 1 block, parallel histogram + packed scan + scatter ----
__global__ __launch_bounds__(256) void prep_v7(const int* __restrict__ ids, int B,
                                               int* __restrict__ sorted,
                                               int* __restrict__ cm,
                                               int* __restrict__ cs0,
                                               int* __restrict__ ccnt,
                                               int* __restrict__ ncp) {
  __shared__ int cnt[NMODELS];
  __shared__ int scan[NMODELS];
  __shared__ int pos[NMODELS];
  const int t = threadIdx.x;
  if (t < NMODELS) cnt[t] = 0;
  __syncthreads();

  const int4* idv = (const int4*)ids;  // B % 4 == 0
  const int n4 = B >> 2;
  for (int e = t; e < n4; e += 256) {
    const int4 r = idv[e];
    atomicAdd(&cnt[r.x], 1);
    atomicAdd(&cnt[r.y], 1);
    atomicAdd(&cnt[r.z], 1);
    atomicAdd(&cnt[r.w], 1);
  }
  __syncthreads();

  // packed inclusive scan: low 16 = samples, high 16 = chunks
  if (t < NMODELS) {
    const int c = cnt[t];
    scan[t] = c + ((((c + CHUNK - 1) / CHUNK) & 0xFFFF) << 16);
  }
  __syncthreads();
  for (int d = 1; d < NMODELS; d <<= 1) {
    int add = 0;
    if (t < NMODELS && t >= d) add = scan[t - d];
    __syncthreads();
    if (t < NMODELS) scan[t] += add;
    __syncthreads();
  }
  if (t == 0) *ncp = scan[NMODELS - 1] >> 16;
  if (t < NMODELS) {
    const int n = cnt[t];
    const int nch = (n + CHUNK - 1) / CHUNK;
    const int off_m = (scan[t] & 0xFFFF) - n;
    const int coff_m = (scan[t] >> 16) - nch;
    pos[t] = off_m;
    for (int c = 0; c < nch; ++c) {
      cm[coff_m + c] = t;
      cs0[coff_m + c] = off_m + c * CHUNK;
      const int rem = n - c * CHUNK;
      ccnt[coff_m + c] = rem < CHUNK ? rem : CHUNK;
    }
  }
  __syncthreads();
  for (int e = t; e < n4; e += 256) {
    const int4 r = idv[e];
    const int b = e * 4;
    sorted[atomicAdd(&pos[r.x], 1)] = b;
    sorted[atomicAdd(&pos[r.y], 1)] = b + 1;
    sorted[atomicAdd(&pos[r.z], 1)] = b + 2;
    sorted[atomicAdd(&pos[r.w], 1)] = b + 3;
  }
}

// ---------- Main: block = one 8-sample chunk, 8 waves ----------
// wave wv: kq = wv>>1 (64-k quarter), ch = wv&1 (128-col half) -> every
// wave reads a DISJOINT W slice (W read exactly once per block).
// lane owns 2 cols (f32x2, coalesced) x 8 samples x 64 k -> acc = 16 VGPR.
// __launch_bounds__(512,4): VGPR cap 128 so acc+w0+w1 stay in registers
// (R4's VGPR=44 squeeze fissioned the loop into serialized load->wait->FMA).
// K-quarters reduced through LDS; pure fp32, k ascending -> exact.
__global__ __launch_bounds__(NT, 4) void linmulti_v7(
    const float* __restrict__ inp, const float* __restrict__ wlut,
    const float* __restrict__ blut, const int* __restrict__ sorted,
    const int* __restrict__ cm, const int* __restrict__ cs0,
    const int* __restrict__ ccnt, const int* __restrict__ ncp,
    float* __restrict__ out) {
  const int cj = blockIdx.x;
  if (cj >= *ncp) return;
  const int m = cm[cj];
  const int s0 = cs0[cj];
  const int scnt = ccnt[cj];
  const int tid = threadIdx.x;

  __shared__ float As[CHUNK * SZ_IN];       // 8 KB
  __shared__ float red[3 * CHUNK * SZ_OUT]; // 24 KB (kq=1,2,3 partials)
  __shared__ int sidx[CHUNK];

  if (tid < CHUNK) {
    const int p = (tid < scnt) ? tid : (scnt - 1);  // clamp pads
    sidx[tid] = sorted[s0 + p];
  }
  __syncthreads();
  {  // stage A: 512 float4, exactly 1 per thread, coalesced
    const int s = tid >> 6, f4 = tid & 63;
    ((f32x4*)As)[tid] = ((const f32x4*)(inp + (size_t)sidx[s] * SZ_IN))[f4];
  }
  __syncthreads();

  const int lane = tid & 63;
  const int wv = tid >> 6;
  const int ch = wv & 1;
  const int kq = wv >> 1;
  const int c2 = ch * 128 + lane * 2;  // global col (f32x2)
  const int kb = kq * 64;
  const float* __restrict__ Wc =
      wlut + (size_t)m * (SZ_IN * SZ_OUT) + (size_t)kb * SZ_OUT + c2;

  f32x2 acc[CHUNK];
#pragma unroll
  for (int s = 0; s < CHUNK; ++s) acc[s] = (f32x2){0.f, 0.f};

  f32x2 w0[8];
#pragma unroll
  for (int j = 0; j < 8; ++j) w0[j] = *(const f32x2*)(Wc + (size_t)j * SZ_OUT);

#pragma unroll 1
  for (int i0 = 0; i0 < 64; i0 += 8) {
    const int nxt = (i0 + 8) & 63;  // wraps on last iter; harmless
    f32x2 w1[8];
#pragma unroll
    for (int j = 0; j < 8; ++j)
      w1[j] = *(const f32x2*)(Wc + (size_t)(nxt + j) * SZ_OUT);

#pragma unroll
    for (int s = 0; s < CHUNK; ++s) {
      const float* ar = As + s * SZ_IN + kb + i0;
      const f32x4 a0 = *(const f32x4*)ar;        // wave-uniform broadcast
      const f32x4 a1 = *(const f32x4*)(ar + 4);
#pragma unroll
      for (int j = 0; j < 4; ++j) {
        acc[s][0] = fmaf(a0[j], w0[j][0], acc[s][0]);
        acc[s][1] = fmaf(a0[j], w0[j][1], acc[s][1]);
      }
#pragma unroll
      for (int j = 0; j < 4; ++j) {
        acc[s][0] = fmaf(a1[j], w0[4 + j][0], acc[s][0]);
        acc[s][1] = fmaf(a1[j], w0[4 + j][1], acc[s][1]);
      }
    }
#pragma unroll
    for (int j = 0; j < 8; ++j) w0[j] = w1[j];
  }

  // 4-way K reduce: kq 1..3 write partials, barrier, kq 0 combines.
  if (kq > 0) {
#pragma unroll
    for (int s = 0; s < CHUNK; ++s)
      *(f32x2*)(red + (kq - 1) * (CHUNK * SZ_OUT) + s * SZ_OUT + c2) = acc[s];
  }
  __syncthreads();
  if (kq == 0) {
    const f32x2 bias2 = *(const f32x2*)(blut + m * SZ_OUT + c2);
#pragma unroll
    for (int s = 0; s < CHUNK; ++s) {
      if (s < scnt) {
        const f32x2 p1 = *(const f32x2*)(red + 0 * (CHUNK * SZ_OUT) + s * SZ_OUT + c2);
        const f32x2 p2 = *(const f32x2*)(red + 1 * (CHUNK * SZ_OUT) + s * SZ_OUT + c2);
        const f32x2 p3 = *(const f32x2*)(red + 2 * (CHUNK * SZ_OUT) + s * SZ_OUT + c2);
        f32x2 r;
        r[0] = acc[s][0] + p1[0] + p2[0] + p3[0] + bias2[0];
        r[1] = acc[s][1] + p1[1] + p2[1] + p3[1] + bias2[1];
        *(f32x2*)(out + (size_t)sidx[s] * SZ_OUT + c2) = r;
      }
    }
  }
}

extern "C" void kernel_launch(void* const* d_in, const int* in_sizes, int n_in,
                              void* d_out, int out_size, void* d_ws, size_t ws_size,
                              hipStream_t stream) {
  const float* inp = (const float*)d_in[0];
  const int* ids = (const int*)d_in[1];
  const float* wlut = (const float*)d_in[2];
  const float* blut = (const float*)d_in[3];
  float* out = (float*)d_out;
  const int B = in_sizes[1];

  int* w = (int*)d_ws;
  int* sorted = w;             // B ints
  int* cm = w + 4096;          // MAXCHUNKS
  int* cs0 = cm + MAXCHUNKS;
  int* ccnt = cs0 + MAXCHUNKS;
  int* ncp = ccnt + MAXCHUNKS;

  prep_v7<<<1, 256, 0, stream>>>(ids, B, sorted, cm, cs0, ccnt, ncp);
  linmulti_v7<<<MAXCHUNKS, NT, 0, stream>>>(inp, wlut, blut, sorted, cm, cs0,
                                            ccnt, ncp, out);
}

// Round 8
// 96.041 us; speedup vs baseline: 1.1828x; 1.1828x over previous
//
#include <hip/hip_runtime.h>

#define NMODELS 128
#define SZ_IN 256
#define SZ_OUT 256
#define CHUNK 16
#define MAXCHUNKS 384  // >= 128 + 4096/16 worst case
#define LDSK 264       // bf16 row stride: 528 B -> bank-stride 4, 2-way alias (free)

typedef __attribute__((ext_vector_type(4))) float f32x4;
typedef __attribute__((ext_vector_type(8))) short bf16x8;
typedef __attribute__((ext_vector_type(4))) short s16x4;

// fp32 -> bf16 RNE (bit pattern)
__device__ __forceinline__ short f2bf(float f) {
  union { float f; unsigned u; } v;
  v.f = f;
  const unsigned r = v.u + 0x7FFFu + ((v.u >> 16) & 1u);
  return (short)(r >> 16);
}

// ---------- Prep (proven in v5-v7): 1 block, histogram + packed scan ----------
__global__ __launch_bounds__(256) void prep_v8(const int* __restrict__ ids, int B,
                                               int* __restrict__ sorted,
                                               int* __restrict__ cm,
                                               int* __restrict__ cs0,
                                               int* __restrict__ ccnt,
                                               int* __restrict__ ncp) {
  __shared__ int cnt[NMODELS];
  __shared__ int scan[NMODELS];
  __shared__ int pos[NMODELS];
  const int t = threadIdx.x;
  if (t < NMODELS) cnt[t] = 0;
  __syncthreads();
  const int4* idv = (const int4*)ids;  // B % 4 == 0
  const int n4 = B >> 2;
  for (int e = t; e < n4; e += 256) {
    const int4 r = idv[e];
    atomicAdd(&cnt[r.x], 1);
    atomicAdd(&cnt[r.y], 1);
    atomicAdd(&cnt[r.z], 1);
    atomicAdd(&cnt[r.w], 1);
  }
  __syncthreads();
  if (t < NMODELS) {
    const int c = cnt[t];
    scan[t] = c + ((((c + CHUNK - 1) / CHUNK) & 0xFFFF) << 16);
  }
  __syncthreads();
  for (int d = 1; d < NMODELS; d <<= 1) {
    int add = 0;
    if (t < NMODELS && t >= d) add = scan[t - d];
    __syncthreads();
    if (t < NMODELS) scan[t] += add;
    __syncthreads();
  }
  if (t == 0) *ncp = scan[NMODELS - 1] >> 16;
  if (t < NMODELS) {
    const int n = cnt[t];
    const int nch = (n + CHUNK - 1) / CHUNK;
    const int off_m = (scan[t] & 0xFFFF) - n;
    const int coff_m = (scan[t] >> 16) - nch;
    pos[t] = off_m;
    for (int c = 0; c < nch; ++c) {
      cm[coff_m + c] = t;
      cs0[coff_m + c] = off_m + c * CHUNK;
      const int rem = n - c * CHUNK;
      ccnt[coff_m + c] = rem < CHUNK ? rem : CHUNK;
    }
  }
  __syncthreads();
  for (int e = t; e < n4; e += 256) {
    const int4 r = idv[e];
    const int b = e * 4;
    sorted[atomicAdd(&pos[r.x], 1)] = b;
    sorted[atomicAdd(&pos[r.y], 1)] = b + 1;
    sorted[atomicAdd(&pos[r.z], 1)] = b + 2;
    sorted[atomicAdd(&pos[r.w], 1)] = b + 3;
  }
}

// ---------- Main: MFMA. block = (chunk, 128-col half), 4 waves x 2 n-tiles ----
// mfma_f32_16x16x32_bf16 layouts (doc m89/m91, now decoupled from the R2 list bug):
//   A[m = lane&15][k = q*8 + j]   (q = lane>>4, j = 0..7)  -> one ds_read_b128
//   B[k = q*8 + j][n = lane&15]   -> 8 strided global dwords + cvt, per tile
//   D[row = q*4 + r][col = lane&15]
// M-dim = 16 chunk samples, N = out cols, K = sz_in.
__global__ __launch_bounds__(256, 4) void linmulti_v8(
    const float* __restrict__ inp, const float* __restrict__ wlut,
    const float* __restrict__ blut, const int* __restrict__ sorted,
    const int* __restrict__ cm, const int* __restrict__ cs0,
    const int* __restrict__ ccnt, const int* __restrict__ ncp,
    float* __restrict__ out) {
  const int cj = blockIdx.x >> 1;
  if (cj >= *ncp) return;
  const int ch = blockIdx.x & 1;  // col half
  const int m = cm[cj];
  const int s0 = cs0[cj];
  const int scnt = ccnt[cj];
  const int tid = threadIdx.x;

  __shared__ short As[CHUNK * LDSK];  // bf16 A-tile, padded rows (8448 B)
  __shared__ int sidx[CHUNK];

  if (tid < CHUNK) {
    const int p = (tid < scnt) ? tid : (scnt - 1);  // clamp pad rows
    sidx[tid] = sorted[s0 + p];
  }
  __syncthreads();
  // stage A: 4096 floats as 1024 f32x4 (4/thread, coalesced) -> bf16 LDS
#pragma unroll
  for (int v = 0; v < 4; ++v) {
    const int e4 = v * 256 + tid;
    const int s = e4 >> 6, f4 = e4 & 63;
    const f32x4 a = ((const f32x4*)(inp + (size_t)sidx[s] * SZ_IN))[f4];
    s16x4 h;
#pragma unroll
    for (int j = 0; j < 4; ++j) h[j] = f2bf(a[j]);
    *(s16x4*)(As + s * LDSK + f4 * 4) = h;
  }
  __syncthreads();

  const int lane = tid & 63;
  const int wv = tid >> 6;
  const int q = lane >> 4;
  const int n16 = lane & 15;
  const int colbase = ch * 128 + wv * 32;  // wave owns 32 cols = 2 tiles
  const float* __restrict__ Wm = wlut + (size_t)m * (SZ_IN * SZ_OUT);

  f32x4 acc[2];
  acc[0] = (f32x4){0.f, 0.f, 0.f, 0.f};
  acc[1] = (f32x4){0.f, 0.f, 0.f, 0.f};

#pragma unroll 2
  for (int k0 = 0; k0 < SZ_IN; k0 += 32) {
    const int ka = k0 + q * 8;
    // A fragment: 8 consecutive bf16 = 16 B
    const bf16x8 afr = *(const bf16x8*)(As + (n16)*LDSK + ka);
    // B fragments: 2 tiles x 8 k-rows (stride SZ_OUT), col = colbase+16t+n16
    float bw[2][8];
#pragma unroll
    for (int t = 0; t < 2; ++t) {
      const float* __restrict__ Bp = Wm + (size_t)ka * SZ_OUT + colbase + t * 16 + n16;
#pragma unroll
      for (int j = 0; j < 8; ++j) bw[t][j] = Bp[(size_t)j * SZ_OUT];
    }
#pragma unroll
    for (int t = 0; t < 2; ++t) {
      bf16x8 bfr;
#pragma unroll
      for (int j = 0; j < 8; ++j) bfr[j] = f2bf(bw[t][j]);
      acc[t] = __builtin_amdgcn_mfma_f32_16x16x32_bf16(afr, bfr, acc[t], 0, 0, 0);
    }
  }

  // Epilogue: D[row=q*4+r][col], row -> sample sidx[q*4+r]
#pragma unroll
  for (int t = 0; t < 2; ++t) {
    const int col = colbase + t * 16 + n16;
    const float bias_c = blut[m * SZ_OUT + col];
#pragma unroll
    for (int r = 0; r < 4; ++r) {
      const int srow = q * 4 + r;
      if (srow < scnt) {
        out[(size_t)sidx[srow] * SZ_OUT + col] = acc[t][r] + bias_c;
      }
    }
  }
}

extern "C" void kernel_launch(void* const* d_in, const int* in_sizes, int n_in,
                              void* d_out, int out_size, void* d_ws, size_t ws_size,
                              hipStream_t stream) {
  const float* inp = (const float*)d_in[0];
  const int* ids = (const int*)d_in[1];
  const float* wlut = (const float*)d_in[2];
  const float* blut = (const float*)d_in[3];
  float* out = (float*)d_out;
  const int B = in_sizes[1];

  int* w = (int*)d_ws;
  int* sorted = w;             // B ints
  int* cm = w + 4096;          // MAXCHUNKS
  int* cs0 = cm + MAXCHUNKS;
  int* ccnt = cs0 + MAXCHUNKS;
  int* ncp = ccnt + MAXCHUNKS;

  prep_v8<<<1, 256, 0, stream>>>(ids, B, sorted, cm, cs0, ccnt, ncp);
  linmulti_v8<<<2 * MAXCHUNKS, 256, 0, stream>>>(inp, wlut, blut, sorted, cm,
                                                 cs0, ccnt, ncp, out);
}